// Round 10
// baseline (2273.080 us; speedup 1.0000x reference)
//
#include <hip/hip_runtime.h>
#include <math.h>

// Problem constants
#define NN 4096
#define TT 48
#define HH 64
#define GG 256   // 4*H
#define PP 12
#define CAP 192  // ELL slots per row, 3 x 64 -> whole-wave chunk loads, no guard
#define NH (NN * HH)

// readlane broadcast: uniform lane index -> SGPR broadcast, off the LDS pipe
__device__ __forceinline__ float bcast_f(float v, int lane) {
  return __int_as_float(__builtin_amdgcn_readlane(__float_as_int(v), lane));
}
__device__ __forceinline__ int bcast_i(int v, int lane) {
  return __builtin_amdgcn_readlane(v, lane);
}

// ---------------------------------------------------------------------------
// h-state: paired buffers P[2], each [N][64][2]: {h0, h1} interleaved.
// Launch k (k=0..48) computes cell0(t=k) [k<48] and cell1(s=k-1) [k>0]:
//   READS only P[(k&1)^1], WRITES only P[k&1] (disjoint float2 slots).
// Final h1(47) in P[0].y.
//
// R9: R7's merged-role kernel with 4 ROWS PER WAVE (16 rows/block, grid 256).
// Evidence chain: R7 40us @ 2 rows/wave: LDS pipe = 8 waves/CU x 384 KB
// weight reads = 3 MB/CU ~ 15us (dominant serial resource) + ~15us VALU,
// poorly overlapped. R8 (32 KB chunks, 12 barriers) was neutral -> barriers
// NOT the stall; LDS traffic is. Per-wave weight LDS bytes are fixed (all
// 64 k x own quad x both cells); ONLY rows/wave amortizes them. 4 rows/wave:
// per-CU LDS weight traffic halves (1.5 MB ~ 7.5us), FMA per b128 pair
// doubles (16->32, VALU-dominant dense loop), total VALU unchanged. Cost:
// 1024 waves = 4/CU = 1 wave/SIMD (R2's danger zone) -- accepted because
// dense reads now come from LDS (short latency, deep unroll ILP) with
// weights prefetched a chunk ahead (~900cy compute cover), unlike R2's
// L2-streamed weights. Failure read pre-committed: dur >= 38us &
// VALUBusy < 32% -> revert to R7, declare structural floor.
// History: R0 48.5 -> R6 42.4 (unroll-1 ping-pong staging; R4/R5 lesson:
// constant-trip ch-loops MUST be #pragma unroll 1 or prefetch hoists ->
// VGPR 256 + scratch) -> R7 40.0 (merged roles, gather once) -> R8 ~40.
// Per-row FP order identical to R7.
//
// GATE-QUAD mapping: lane j owns cols {j, j+64, j+128, j+192} = (i,f,o,g) of
// hidden unit j. Full quad in one lane's float4 acc.
//   Wg[(k*2+m)*64+j]        = cell0 quads, m in {gcWh0, liWh0}   (8192 f4)
//   Wg[8192+(k*4+m)*64+j]   = cell1 quads, m in {gcWi1, liWi1, gcWh1, liWh1}
// ---------------------------------------------------------------------------
__launch_bounds__(256)
__global__ void k_prep(const float* gcbi0, const float* gcbh0,
                       const float* libi0, const float* libh0,
                       const float* gcbi1, const float* gcbh1,
                       const float* libi1, const float* libh1,
                       const float* gcWh0, const float* liWh0,
                       const float* gcWi1, const float* liWi1,
                       const float* gcWh1, const float* liWh1,
                       const float* gcWi0, const float* liWi0,
                       float* state, float4* Wg0, float4* Wg1,
                       float4* biasg0, float4* biasg1, float4* xq0) {
  int idx = blockIdx.x * 256 + threadIdx.x;
  int stride = gridDim.x * 256;
  for (int i = idx; i < 6 * NH; i += stride) state[i] = 0.0f;  // P0,P1,c0,c1
  for (int i = idx; i < 64 * 2 * 64; i += stride) {
    int j = i & 63, m = (i >> 6) & 1, k = i >> 7;
    const float* W = m ? liWh0 : gcWh0;
    Wg0[i] = make_float4(W[k * GG + j], W[k * GG + j + 64],
                         W[k * GG + j + 128], W[k * GG + j + 192]);
  }
  for (int i = idx; i < 64 * 4 * 64; i += stride) {
    int j = i & 63, m = (i >> 6) & 3, k = i >> 8;
    const float* W = (m == 0) ? gcWi1 : (m == 1) ? liWi1 : (m == 2) ? gcWh1 : liWh1;
    Wg1[i] = make_float4(W[k * GG + j], W[k * GG + j + 64],
                         W[k * GG + j + 128], W[k * GG + j + 192]);
  }
  if (idx < 64) {
    int j = idx;
    biasg0[j] = make_float4(
        gcbi0[j] + gcbh0[j] + libi0[j] + libh0[j],
        gcbi0[j + 64] + gcbh0[j + 64] + libi0[j + 64] + libh0[j + 64],
        gcbi0[j + 128] + gcbh0[j + 128] + libi0[j + 128] + libh0[j + 128],
        gcbi0[j + 192] + gcbh0[j + 192] + libi0[j + 192] + libh0[j + 192]);
    biasg1[j] = make_float4(
        gcbi1[j] + gcbh1[j] + libi1[j] + libh1[j],
        gcbi1[j + 64] + gcbh1[j + 64] + libi1[j + 64] + libh1[j + 64],
        gcbi1[j + 128] + gcbh1[j + 128] + libi1[j + 128] + libh1[j + 128],
        gcbi1[j + 192] + gcbh1[j + 192] + libi1[j + 192] + libh1[j + 192]);
  } else if (idx < 320) {
    int i = idx - 64;           // i = m*64 + j
    int j = i & 63, m = i >> 6; // m: 0,1 -> gcWi0 row 0/1; 2,3 -> liWi0 row 0/1
    const float* W = (m < 2) ? gcWi0 : liWi0;
    int kk = m & 1;
    xq0[i] = make_float4(W[kk * GG + j], W[kk * GG + j + 64],
                         W[kk * GG + j + 128], W[kk * GG + j + 192]);
  }
}

// ---------------------------------------------------------------------------
// Single adj pass: raw ELL (incl. +I diag) + dinv. Zero-fills ALL CAP slots
// (re-poison semantics: padding must be (col=0, val=0)). cnt padded to x8.
// ---------------------------------------------------------------------------
__launch_bounds__(256)
__global__ void k_build(const float* adj, float* dinv,
                        int* ell_col, float* ell_val, int* ell_cnt) {
  int r = blockIdx.x;
  __shared__ int cnt;
  __shared__ float red[256];
  if (threadIdx.x == 0) cnt = 0;
  __syncthreads();
  const float* row = adj + (size_t)r * NN;
  float s = 0.0f;
  for (int c = threadIdx.x; c < NN; c += 256) {
    float a = row[c];
    if (c == r) a += 1.0f;   // A = adj + I
    s += a;
    if (a != 0.0f) {
      int pos = atomicAdd(&cnt, 1);
      if (pos < CAP) {
        ell_col[(size_t)r * CAP + pos] = c;
        ell_val[(size_t)r * CAP + pos] = a;
      }
    }
  }
  red[threadIdx.x] = s;
  __syncthreads();
  for (int st = 128; st > 0; st >>= 1) {
    if (threadIdx.x < st) red[threadIdx.x] += red[threadIdx.x + st];
    __syncthreads();
  }
  int n = cnt < CAP ? cnt : CAP;
  for (int j = n + (int)threadIdx.x; j < CAP; j += 256) {
    ell_col[(size_t)r * CAP + j] = 0;
    ell_val[(size_t)r * CAP + j] = 0.0f;
  }
  if (threadIdx.x == 0) {
    int npad = (n + 7) & ~7;
    if (npad > CAP) npad = CAP;
    ell_cnt[r] = npad;
    dinv[r] = 1.0f / sqrtf(red[0]);  // rowsum + 1 >= 1
  }
}

__launch_bounds__(256)
__global__ void k_scale(const float* dinv, const int* ell_col, float* ell_val) {
  int idx = blockIdx.x * 256 + threadIdx.x;  // over NN*CAP
  int r = idx / CAP;
  if (r >= NN) return;
  float v = ell_val[idx];
  if (v != 0.0f) ell_val[idx] = v * dinv[r] * dinv[ell_col[idx]];
}

// ---------------------------------------------------------------------------
// Precompute gax[t][r][c] = (A @ x_t)[r][c]. Block = (t, 512-row segment).
// ---------------------------------------------------------------------------
__launch_bounds__(256)
__global__ void k_gax(const float* x, const int* ell_col, const float* ell_val,
                      const int* ell_cnt, float* gax) {
  int t = blockIdx.x >> 3;
  int seg = blockIdx.x & 7;
  __shared__ float xs[NN * 2];
  const float* xt = x + (size_t)t * NN * 2;
  for (int i = threadIdx.x; i < NN * 2; i += 256) xs[i] = xt[i];
  __syncthreads();
  int base = seg * 512 * 2;
  for (int oo = threadIdx.x; oo < 512 * 2; oo += 256) {
    int o = base + oo;
    int r = o >> 1, cmp = o & 1;
    int cnt = ell_cnt[r];
    const int* cp = ell_col + (size_t)r * CAP;
    const float* vp = ell_val + (size_t)r * CAP;
    float acc = 0.0f;
    for (int j = 0; j < cnt; j += 4) {
      acc += vp[j]     * xs[cp[j]     * 2 + cmp];
      acc += vp[j + 1] * xs[cp[j + 1] * 2 + cmp];
      acc += vp[j + 2] * xs[cp[j + 2] * 2 + cmp];
      acc += vp[j + 3] * xs[cp[j + 3] * 2 + cmp];
    }
    gax[(size_t)t * NN * 2 + o] = acc;
  }
}

// ---------------------------------------------------------------------------
// Merged step kernel: one block = 16 rows = 4 waves x 4 rows, BOTH roles.
// Phase 1: single gather {ga0=A@Pr.x, ga1=A@Pr.y, hl0, hl1} for 4 rows/wave.
// Phase 2: loop A = Wg0, 8 chunks x 8 k (acc0); cell0 epilogue; loop B =
// Wg1, 16 chunks x 4 k (acc1); cell1 epilogue. Unroll-1 ping-pong prefetch
// chain across both loops; 2 x 16 KB LDS.
// ---------------------------------------------------------------------------
__launch_bounds__(256)
__global__ void k_cells(int c0on, int c1on,
                        const int* __restrict__ ell_col,
                        const float* __restrict__ ell_val,
                        const int* __restrict__ ell_cnt,
                        const float2* __restrict__ Pr, float* __restrict__ Pw,
                        float* __restrict__ c0, float* __restrict__ c1,
                        const float* __restrict__ xt, const float* __restrict__ gaxt,
                        const float4* __restrict__ Wg,
                        const float4* __restrict__ biasg0,
                        const float4* __restrict__ xq0,
                        const float4* __restrict__ biasg1) {
  __shared__ float4 wbuf[2048];  // 2 x 16 KB ping-pong
  const int tid = threadIdx.x;
  const int wave = tid >> 6, lane = tid & 63;
  const int r0 = blockIdx.x * 16 + wave * 4;

  // chunk-0 prefetch: completes under the gather phase
  const float4* pf = Wg + tid;
  float4 st0 = pf[0], st1 = pf[256], st2 = pf[512], st3 = pf[768];
  pf += 1024;

  // early c-state loads (latency hidden under gather)
  float cprev0[4], cprev1[4];
#pragma unroll
  for (int rr = 0; rr < 4; rr++) {
    size_t gi = (size_t)(r0 + rr) * HH + lane;
    cprev0[rr] = c0[gi];
    cprev1[rr] = c1[gi];
  }

  int myc[4][3]; float myv[4][3]; int cnts[4];
#pragma unroll
  for (int rr = 0; rr < 4; rr++) {
    int r = r0 + rr;
    cnts[rr] = ell_cnt[r];
#pragma unroll
    for (int chk = 0; chk < 3; chk++) {
      myc[rr][chk] = ell_col[(size_t)r * CAP + chk * 64 + lane];
      myv[rr][chk] = ell_val[(size_t)r * CAP + chk * 64 + lane];
    }
  }

  // single gather pass: both float2 components, 4 rows
  float ga0[4], ga1[4], hl0[4], hl1[4];
#pragma unroll
  for (int rr = 0; rr < 4; rr++) {
    int cnt = cnts[rr];
    float a0 = 0.0f, a1 = 0.0f;
#pragma unroll
    for (int chk = 0; chk < 3; chk++) {
      int base = chk * 64;
      if (base < cnt) {
        int lim = cnt - base; if (lim > 64) lim = 64;  // multiple of 8
        int mc = myc[rr][chk]; float mv = myv[rr][chk];
        for (int m = 0; m < lim; m += 8) {
          float2 ld[8]; float vv[8];
#pragma unroll
          for (int i = 0; i < 8; i++) {
            int cc = bcast_i(mc, m + i);
            vv[i] = bcast_f(mv, m + i);
            ld[i] = Pr[(size_t)cc * 64 + lane];
          }
#pragma unroll
          for (int i = 0; i < 8; i++) {
            a0 += vv[i] * ld[i].x;
            a1 += vv[i] * ld[i].y;
          }
        }
      }
    }
    ga0[rr] = a0;   // A @ h0(k-1)  -- shared by cell0 (gcWh0) and cell1 (gcWi1)
    ga1[rr] = a1;   // A @ h1(k-2)  -- cell1 (gcWh1)
    float2 hh = Pr[(size_t)(r0 + rr) * 64 + lane];
    hl0[rr] = hh.x; // h0(k-1)      -- cell0 (liWh0) and cell1 (liWi1)
    hl1[rr] = hh.y; // h1(k-2)      -- cell1 (liWh1)
  }

  // accumulator inits
  float4 acc0[4], acc1[4];
  {
    float4 b = biasg0[lane];
    float4 qg0 = xq0[lane], qg1 = xq0[64 + lane];
    float4 ql0 = xq0[128 + lane], ql1 = xq0[192 + lane];
#pragma unroll
    for (int rr = 0; rr < 4; rr++) {
      float xx0 = xt[(size_t)(r0 + rr) * 2];
      float xx1 = xt[(size_t)(r0 + rr) * 2 + 1];
      float gg0 = gaxt[(size_t)(r0 + rr) * 2];
      float gg1 = gaxt[(size_t)(r0 + rr) * 2 + 1];
      acc0[rr].x = b.x + gg0 * qg0.x + gg1 * qg1.x + xx0 * ql0.x + xx1 * ql1.x;
      acc0[rr].y = b.y + gg0 * qg0.y + gg1 * qg1.y + xx0 * ql0.y + xx1 * ql1.y;
      acc0[rr].z = b.z + gg0 * qg0.z + gg1 * qg1.z + xx0 * ql0.z + xx1 * ql1.z;
      acc0[rr].w = b.w + gg0 * qg0.w + gg1 * qg1.w + xx0 * ql0.w + xx1 * ql1.w;
    }
    float4 b1 = biasg1[lane];
#pragma unroll
    for (int rr = 0; rr < 4; rr++) acc1[rr] = b1;
  }

  // stage chunk 0, enter pipeline
  wbuf[tid] = st0; wbuf[256 + tid] = st1;
  wbuf[512 + tid] = st2; wbuf[768 + tid] = st3;
  __syncthreads();
  int cur = 0;

  // loop A: Wg0, 8 chunks x 8 k; ALWAYS prefetch next (ch=7 pulls in Wg1
  // chunk 0 so the chain crosses the loop boundary seamlessly)
#pragma unroll 1
  for (int ch = 0; ch < 8; ch++) {
    st0 = pf[0]; st1 = pf[256]; st2 = pf[512]; st3 = pf[768];
    pf += 1024;
    const float4* wb = wbuf + (cur << 10);
#pragma unroll
    for (int kk = 0; kk < 8; kk++) {
      int k = ch * 8 + kk;
      float4 w0 = wb[(kk * 2 + 0) * 64 + lane];
      float4 w1 = wb[(kk * 2 + 1) * 64 + lane];
#pragma unroll
      for (int rr = 0; rr < 4; rr++) {
        float a0 = bcast_f(ga0[rr], k);
        float a1 = bcast_f(hl0[rr], k);
        acc0[rr].x += a0 * w0.x + a1 * w1.x;
        acc0[rr].y += a0 * w0.y + a1 * w1.y;
        acc0[rr].z += a0 * w0.z + a1 * w1.z;
        acc0[rr].w += a0 * w0.w + a1 * w1.w;
      }
    }
    cur ^= 1;
    float4* dst = wbuf + (cur << 10) + tid;
    dst[0] = st0; dst[256] = st1; dst[512] = st2; dst[768] = st3;
    __syncthreads();  // writes visible; all waves past chunk ch
  }

  // cell0 epilogue: stores issued here overlap loop B
  if (c0on) {
#pragma unroll
    for (int rr = 0; rr < 4; rr++) {
      size_t gi = (size_t)(r0 + rr) * HH + lane;
      float si = 1.0f / (1.0f + __expf(-acc0[rr].x));
      float sf = 1.0f / (1.0f + __expf(-acc0[rr].y));
      float so = 1.0f / (1.0f + __expf(-acc0[rr].z));
      float cn = sf * cprev0[rr] + si * tanhf(acc0[rr].w);
      float hn = so * tanhf(cn);
      c0[gi] = cn;
      Pw[gi * 2 + 0] = hn;
    }
  }

  // loop B: Wg1, 16 chunks x 4 k; buf[cur] already holds Wg1 chunk 0
  if (c1on) {
#pragma unroll 1
    for (int ch = 0; ch < 16; ch++) {
      if (ch + 1 < 16) {
        st0 = pf[0]; st1 = pf[256]; st2 = pf[512]; st3 = pf[768];
        pf += 1024;
      }
      const float4* wb = wbuf + (cur << 10);
#pragma unroll
      for (int kk = 0; kk < 4; kk++) {
        int k = ch * 4 + kk;
        float4 w0 = wb[(kk * 4 + 0) * 64 + lane];
        float4 w1 = wb[(kk * 4 + 1) * 64 + lane];
        float4 w2 = wb[(kk * 4 + 2) * 64 + lane];
        float4 w3 = wb[(kk * 4 + 3) * 64 + lane];
#pragma unroll
        for (int rr = 0; rr < 4; rr++) {
          float a0 = bcast_f(ga0[rr], k);   // (A@h0new)  -> gcWi1
          float a1 = bcast_f(hl0[rr], k);   // h0new      -> liWi1
          float a2 = bcast_f(ga1[rr], k);   // (A@h1old)  -> gcWh1
          float a3 = bcast_f(hl1[rr], k);   // h1old      -> liWh1
          acc1[rr].x += a0 * w0.x + a1 * w1.x + a2 * w2.x + a3 * w3.x;
          acc1[rr].y += a0 * w0.y + a1 * w1.y + a2 * w2.y + a3 * w3.y;
          acc1[rr].z += a0 * w0.z + a1 * w1.z + a2 * w2.z + a3 * w3.z;
          acc1[rr].w += a0 * w0.w + a1 * w1.w + a2 * w2.w + a3 * w3.w;
        }
      }
      if (ch + 1 < 16) {
        cur ^= 1;
        float4* dst = wbuf + (cur << 10) + tid;
        dst[0] = st0; dst[256] = st1; dst[512] = st2; dst[768] = st3;
        __syncthreads();
      }
    }
#pragma unroll
    for (int rr = 0; rr < 4; rr++) {
      size_t gi = (size_t)(r0 + rr) * HH + lane;
      float si = 1.0f / (1.0f + __expf(-acc1[rr].x));
      float sf = 1.0f / (1.0f + __expf(-acc1[rr].y));
      float so = 1.0f / (1.0f + __expf(-acc1[rr].z));
      float cn = sf * cprev1[rr] + si * tanhf(acc1[rr].w);
      float hn = so * tanhf(cn);
      c1[gi] = cn;
      Pw[gi * 2 + 1] = hn;
    }
  }
}

// ---------------------------------------------------------------------------
// Output projection: out[r,p] = h1[r,:] @ outW[:,p] + outb[p].
// h1 final = P0[..][1] (launch 48 writes P[0].y).
// ---------------------------------------------------------------------------
__launch_bounds__(256)
__global__ void k_out(const float* __restrict__ P0, const float* __restrict__ outW,
                      const float* __restrict__ outb, float* __restrict__ out) {
  int idx = blockIdx.x * 256 + threadIdx.x;
  if (idx >= NN * PP) return;
  int r = idx / PP, p = idx - r * PP;
  float acc = outb[p];
  const float* hrow = P0 + (size_t)r * 128;
#pragma unroll 16
  for (int k = 0; k < HH; k++) acc += hrow[k * 2 + 1] * outW[k * PP + p];
  out[idx] = acc;
}

extern "C" void kernel_launch(void* const* d_in, const int* in_sizes, int n_in,
                              void* d_out, int out_size, void* d_ws, size_t ws_size,
                              hipStream_t stream) {
  const float* x     = (const float*)d_in[0];
  const float* adj   = (const float*)d_in[1];
  const float* gcWi0 = (const float*)d_in[2];
  const float* gcbi0 = (const float*)d_in[3];
  const float* gcWh0 = (const float*)d_in[4];
  const float* gcbh0 = (const float*)d_in[5];
  const float* liWi0 = (const float*)d_in[6];
  const float* libi0 = (const float*)d_in[7];
  const float* liWh0 = (const float*)d_in[8];
  const float* libh0 = (const float*)d_in[9];
  const float* gcWi1 = (const float*)d_in[10];
  const float* gcbi1 = (const float*)d_in[11];
  const float* gcWh1 = (const float*)d_in[12];
  const float* gcbh1 = (const float*)d_in[13];
  const float* liWi1 = (const float*)d_in[14];
  const float* libi1 = (const float*)d_in[15];
  const float* liWh1 = (const float*)d_in[16];
  const float* libh1 = (const float*)d_in[17];
  const float* outW  = (const float*)d_in[18];
  const float* outb  = (const float*)d_in[19];

  char* ws = (char*)d_ws;
  size_t off = 0;
  auto carve = [&](size_t bytes) {
    void* p = ws + off;
    off += (bytes + 255) & ~(size_t)255;
    return p;
  };
  float*  dinv    = (float*)carve((size_t)NN * 4);
  int*    ell_col = (int*)carve((size_t)NN * CAP * 4);
  float*  ell_val = (float*)carve((size_t)NN * CAP * 4);
  int*    ell_cnt = (int*)carve((size_t)NN * 4);
  float*  state   = (float*)carve((size_t)6 * NH * 4);  // P0,P1 (2NH each), c0, c1
  float*  gax     = (float*)carve((size_t)TT * NN * 2 * 4);
  float4* Wgm     = (float4*)carve((size_t)(8192 + 16384) * 16);  // Wg0|Wg1 contiguous
  float4* biasg0  = (float4*)carve((size_t)64 * 16);
  float4* biasg1  = (float4*)carve((size_t)64 * 16);
  float4* xq0     = (float4*)carve((size_t)256 * 16);

  float4* Wg0 = Wgm;
  float4* Wg1 = Wgm + 8192;
  float* P[2] = {state, state + 2 * NH};
  float* c0 = state + 4 * NH;
  float* c1 = state + 5 * NH;

  k_prep<<<512, 256, 0, stream>>>(gcbi0, gcbh0, libi0, libh0,
                                  gcbi1, gcbh1, libi1, libh1,
                                  gcWh0, liWh0, gcWi1, liWi1, gcWh1, liWh1,
                                  gcWi0, liWi0,
                                  state, Wg0, Wg1, biasg0, biasg1, xq0);
  k_build<<<NN, 256, 0, stream>>>(adj, dinv, ell_col, ell_val, ell_cnt);
  k_scale<<<(NN * CAP) / 256, 256, 0, stream>>>(dinv, ell_col, ell_val);
  k_gax<<<TT * 8, 256, 0, stream>>>(x, ell_col, ell_val, ell_cnt, gax);

  // Merged step loop: launch k runs {cell0(k) + cell1(k-1)} per 16-row block.
  // Launch k reads P[(k&1)^1], writes P[k&1].
  for (int k = 0; k <= TT; k++) {
    int A = k & 1;
    int c0on = (k < TT) ? 1 : 0;
    int c1on = (k > 0) ? 1 : 0;
    int tx = (k < TT) ? k : (TT - 1);              // xt/gaxt unused when k==TT
    k_cells<<<NN / 16, 256, 0, stream>>>(
        c0on, c1on, ell_col, ell_val, ell_cnt,
        (const float2*)P[A ^ 1], P[A], c0, c1,
        x + (size_t)tx * NN * 2, gax + (size_t)tx * NN * 2,
        Wgm, biasg0, xq0, biasg1);
  }

  // Launch 48 (A=0) wrote h1(47) into P[0].y
  k_out<<<(NN * PP + 255) / 256, 256, 0, stream>>>(P[0], outW, outb, (float*)d_out);
}

// Round 11
// 1727.819 us; speedup vs baseline: 1.3156x; 1.3156x over previous
//
#include <hip/hip_runtime.h>
#include <math.h>

// Problem constants
#define NN 4096
#define TT 48
#define HH 64
#define GG 256   // 4*H
#define PP 12
#define CAP 192  // ELL slots per row, 3 x 64 -> whole-wave chunk loads, no guard
#define NH (NN * HH)

// readlane broadcast: uniform lane index -> SGPR broadcast, off the LDS pipe
__device__ __forceinline__ float bcast_f(float v, int lane) {
  return __int_as_float(__builtin_amdgcn_readlane(__float_as_int(v), lane));
}
__device__ __forceinline__ int bcast_i(int v, int lane) {
  return __builtin_amdgcn_readlane(v, lane);
}

// ---------------------------------------------------------------------------
// h-state: paired buffers P[2], each [N][64][2]: {h0, h1} interleaved.
// Launch k (k=0..48) computes cell0(t=k) [k<48] and cell1(s=k-1) [k>0]:
//   READS only P[(k&1)^1], WRITES only P[k&1] (disjoint float2 slots).
// Final h1(47) in P[0].y.
//
// R10: MERGED + K-SPLIT + INTERLEAVED WEIGHT LAYOUT. Evidence: R6 (16
// waves/CU, 2x gather, 3 MB/CU LDS) 42.4us; R7 (8 waves/CU, 1x gather,
// 3 MB/CU) 40us; R9 (4 waves/CU, 1.5 MB/CU) 48us -- all latency-bound
// (every pipe <50%), TLP is binding, traffic is not. Missing square:
// merged gather + 16 waves/CU at R7 traffic. Design: 512-thr blocks
// (4 pairs x 2 k-half waves), 8 rows/block, grid 512 -> 4096 waves =
// 16/CU. Wave gathers ONE row (pair exchanges ga via LDS -> gather 1x,
// spread over 2x waves); dense loops: wave computes its k-half for the
// pair's 2 rows. Wg k-dim PERMUTED in k_prep so each 16 KB chunk holds
// 4 k of EACH half -> both kh waves compute on every chunk (R1's idle-
// half flaw fixed). Per-wave LDS reads halve -> per-CU stays 3 MB; 4
// active waves/SIMD per chunk (vs R7's 2). Partial-acc reduction via the
// 8 KB exchange buffer; kh=0 finalizes cell0, kh=1 cell1 (balanced).
// __launch_bounds__(512,4) -> VGPR<=128 (R1's error was (512,8)->32).
// ch-loops #pragma unroll 1 (R4/R5: full unroll hoists prefetch -> VGPR
// 256 + scratch). k-split reassociates the k-sum: absmax ~1e-4 (R1/R5
// precedent passed).
// History: R0 48.5 -> R6 42.4 -> R7 40.0 -> R8 ~40 (chunk size moot) ->
// R9 48 (TLP floor proven).
//
// GATE-QUAD mapping: lane j owns cols {j, j+64, j+128, j+192} = (i,f,o,g)
// of hidden unit j. PERMUTED slot order (chunk-interleaved k-halves):
//   Wg0: slot0(k) = (k%32/4)*8 + (k/32)*4 + (k%4);  f4 = slot*128 + m*64 + j
//        m in {gcWh0, liWh0}; chunk c (8 slots) holds k {4c..4c+3, 32+4c..}
//   Wg1: slot1(k) = (k%32/2)*4 + (k/32)*2 + (k%2);  f4 = 8192 + slot*256
//        + m*64 + j; m in {gcWi1, liWi1, gcWh1, liWh1}; chunk c (4 slots)
//        holds k {2c, 2c+1, 32+2c, 32+2c+1}
// ---------------------------------------------------------------------------
__launch_bounds__(256)
__global__ void k_prep(const float* gcbi0, const float* gcbh0,
                       const float* libi0, const float* libh0,
                       const float* gcbi1, const float* gcbh1,
                       const float* libi1, const float* libh1,
                       const float* gcWh0, const float* liWh0,
                       const float* gcWi1, const float* liWi1,
                       const float* gcWh1, const float* liWh1,
                       const float* gcWi0, const float* liWi0,
                       float* state, float4* Wg0, float4* Wg1,
                       float4* biasg0, float4* biasg1, float4* xq0) {
  int idx = blockIdx.x * 256 + threadIdx.x;
  int stride = gridDim.x * 256;
  for (int i = idx; i < 6 * NH; i += stride) state[i] = 0.0f;  // P0,P1,c0,c1
  for (int i = idx; i < 64 * 2 * 64; i += stride) {
    int j = i & 63, m = (i >> 6) & 1, k = i >> 7;
    const float* W = m ? liWh0 : gcWh0;
    int slot = ((k & 31) >> 2) * 8 + (k >> 5) * 4 + (k & 3);
    Wg0[slot * 128 + m * 64 + j] =
        make_float4(W[k * GG + j], W[k * GG + j + 64],
                    W[k * GG + j + 128], W[k * GG + j + 192]);
  }
  for (int i = idx; i < 64 * 4 * 64; i += stride) {
    int j = i & 63, m = (i >> 6) & 3, k = i >> 8;
    const float* W = (m == 0) ? gcWi1 : (m == 1) ? liWi1 : (m == 2) ? gcWh1 : liWh1;
    int slot = ((k & 31) >> 1) * 4 + (k >> 5) * 2 + (k & 1);
    Wg1[slot * 256 + m * 64 + j] =
        make_float4(W[k * GG + j], W[k * GG + j + 64],
                    W[k * GG + j + 128], W[k * GG + j + 192]);
  }
  if (idx < 64) {
    int j = idx;
    biasg0[j] = make_float4(
        gcbi0[j] + gcbh0[j] + libi0[j] + libh0[j],
        gcbi0[j + 64] + gcbh0[j + 64] + libi0[j + 64] + libh0[j + 64],
        gcbi0[j + 128] + gcbh0[j + 128] + libi0[j + 128] + libh0[j + 128],
        gcbi0[j + 192] + gcbh0[j + 192] + libi0[j + 192] + libh0[j + 192]);
    biasg1[j] = make_float4(
        gcbi1[j] + gcbh1[j] + libi1[j] + libh1[j],
        gcbi1[j + 64] + gcbh1[j + 64] + libi1[j + 64] + libh1[j + 64],
        gcbi1[j + 128] + gcbh1[j + 128] + libi1[j + 128] + libh1[j + 128],
        gcbi1[j + 192] + gcbh1[j + 192] + libi1[j + 192] + libh1[j + 192]);
  } else if (idx < 320) {
    int i = idx - 64;           // i = m*64 + j
    int j = i & 63, m = i >> 6; // m: 0,1 -> gcWi0 row 0/1; 2,3 -> liWi0 row 0/1
    const float* W = (m < 2) ? gcWi0 : liWi0;
    int kk = m & 1;
    xq0[i] = make_float4(W[kk * GG + j], W[kk * GG + j + 64],
                         W[kk * GG + j + 128], W[kk * GG + j + 192]);
  }
}

// ---------------------------------------------------------------------------
// Single adj pass: raw ELL (incl. +I diag) + dinv. Zero-fills ALL CAP slots
// (re-poison semantics: padding must be (col=0, val=0)). cnt padded to x8.
// ---------------------------------------------------------------------------
__launch_bounds__(256)
__global__ void k_build(const float* adj, float* dinv,
                        int* ell_col, float* ell_val, int* ell_cnt) {
  int r = blockIdx.x;
  __shared__ int cnt;
  __shared__ float red[256];
  if (threadIdx.x == 0) cnt = 0;
  __syncthreads();
  const float* row = adj + (size_t)r * NN;
  float s = 0.0f;
  for (int c = threadIdx.x; c < NN; c += 256) {
    float a = row[c];
    if (c == r) a += 1.0f;   // A = adj + I
    s += a;
    if (a != 0.0f) {
      int pos = atomicAdd(&cnt, 1);
      if (pos < CAP) {
        ell_col[(size_t)r * CAP + pos] = c;
        ell_val[(size_t)r * CAP + pos] = a;
      }
    }
  }
  red[threadIdx.x] = s;
  __syncthreads();
  for (int st = 128; st > 0; st >>= 1) {
    if (threadIdx.x < st) red[threadIdx.x] += red[threadIdx.x + st];
    __syncthreads();
  }
  int n = cnt < CAP ? cnt : CAP;
  for (int j = n + (int)threadIdx.x; j < CAP; j += 256) {
    ell_col[(size_t)r * CAP + j] = 0;
    ell_val[(size_t)r * CAP + j] = 0.0f;
  }
  if (threadIdx.x == 0) {
    int npad = (n + 7) & ~7;
    if (npad > CAP) npad = CAP;
    ell_cnt[r] = npad;
    dinv[r] = 1.0f / sqrtf(red[0]);  // rowsum + 1 >= 1
  }
}

__launch_bounds__(256)
__global__ void k_scale(const float* dinv, const int* ell_col, float* ell_val) {
  int idx = blockIdx.x * 256 + threadIdx.x;  // over NN*CAP
  int r = idx / CAP;
  if (r >= NN) return;
  float v = ell_val[idx];
  if (v != 0.0f) ell_val[idx] = v * dinv[r] * dinv[ell_col[idx]];
}

// ---------------------------------------------------------------------------
// Precompute gax[t][r][c] = (A @ x_t)[r][c]. Block = (t, 512-row segment).
// ---------------------------------------------------------------------------
__launch_bounds__(256)
__global__ void k_gax(const float* x, const int* ell_col, const float* ell_val,
                      const int* ell_cnt, float* gax) {
  int t = blockIdx.x >> 3;
  int seg = blockIdx.x & 7;
  __shared__ float xs[NN * 2];
  const float* xt = x + (size_t)t * NN * 2;
  for (int i = threadIdx.x; i < NN * 2; i += 256) xs[i] = xt[i];
  __syncthreads();
  int base = seg * 512 * 2;
  for (int oo = threadIdx.x; oo < 512 * 2; oo += 256) {
    int o = base + oo;
    int r = o >> 1, cmp = o & 1;
    int cnt = ell_cnt[r];
    const int* cp = ell_col + (size_t)r * CAP;
    const float* vp = ell_val + (size_t)r * CAP;
    float acc = 0.0f;
    for (int j = 0; j < cnt; j += 4) {
      acc += vp[j]     * xs[cp[j]     * 2 + cmp];
      acc += vp[j + 1] * xs[cp[j + 1] * 2 + cmp];
      acc += vp[j + 2] * xs[cp[j + 2] * 2 + cmp];
      acc += vp[j + 3] * xs[cp[j + 3] * 2 + cmp];
    }
    gax[(size_t)t * NN * 2 + o] = acc;
  }
}

// ---------------------------------------------------------------------------
// Merged k-split step kernel: 512 threads = 8 waves = 4 pairs x 2 k-halves.
// 8 rows/block (2 per pair). Wave (pair,kh) gathers row r0+kh; pair
// exchanges ga via xbuf; both dense loops computed per k-half on every
// chunk (interleaved layout). kh=0 finalizes cell0, kh=1 cell1.
// LDS: 2 x 16 KB ping-pong + 8 KB exchange/reduction = 40 KB -> 2 blk/CU.
// ---------------------------------------------------------------------------
__launch_bounds__(512, 4)
__global__ void k_cells(int c0on, int c1on,
                        const int* __restrict__ ell_col,
                        const float* __restrict__ ell_val,
                        const int* __restrict__ ell_cnt,
                        const float2* __restrict__ Pr, float* __restrict__ Pw,
                        float* __restrict__ c0, float* __restrict__ c1,
                        const float* __restrict__ xt, const float* __restrict__ gaxt,
                        const float4* __restrict__ Wg,
                        const float4* __restrict__ biasg0,
                        const float4* __restrict__ xq0,
                        const float4* __restrict__ biasg1) {
  __shared__ float4 wbuf[2048];  // 2 x 16 KB ping-pong
  __shared__ float4 xbuf[512];   // 8 KB: ga-exchange (early), acc-reduce (late)
  const int tid = threadIdx.x;
  const int wave = tid >> 6, lane = tid & 63;
  const int pair = wave >> 1, kh = wave & 1;
  const int r0 = blockIdx.x * 8 + pair * 2;
  const int myrow = r0 + kh;

  // chunk-0 prefetch (2 f4/thread): completes under the gather phase
  const float4* pf = Wg + tid;
  float4 st0 = pf[0], st1 = pf[512];
  pf += 1024;

  // c-state loads for the role this wave finalizes (kh=0: cell0, kh=1: cell1)
  float cprevA[2];
#pragma unroll
  for (int rr = 0; rr < 2; rr++) {
    size_t gi = (size_t)(r0 + rr) * HH + lane;
    cprevA[rr] = (kh == 0) ? c0[gi] : c1[gi];
  }

  // gather OWN row (both float2 components)
  int cnt = ell_cnt[myrow];
  int myc[3]; float myv[3];
#pragma unroll
  for (int chk = 0; chk < 3; chk++) {
    myc[chk] = ell_col[(size_t)myrow * CAP + chk * 64 + lane];
    myv[chk] = ell_val[(size_t)myrow * CAP + chk * 64 + lane];
  }
  float a0 = 0.0f, a1 = 0.0f;
#pragma unroll
  for (int chk = 0; chk < 3; chk++) {
    int base = chk * 64;
    if (base < cnt) {
      int lim = cnt - base; if (lim > 64) lim = 64;  // multiple of 8
      int mc = myc[chk]; float mv = myv[chk];
      for (int m = 0; m < lim; m += 8) {
        float2 ld[8]; float vv[8];
#pragma unroll
        for (int i = 0; i < 8; i++) {
          int cc = bcast_i(mc, m + i);
          vv[i] = bcast_f(mv, m + i);
          ld[i] = Pr[(size_t)cc * 64 + lane];
        }
#pragma unroll
        for (int i = 0; i < 8; i++) {
          a0 += vv[i] * ld[i].x;
          a1 += vv[i] * ld[i].y;
        }
      }
    }
  }
  // publish ga for my row; load hl for both rows directly
  {
    float2* gx = (float2*)xbuf;
    gx[(size_t)(pair * 2 + kh) * 64 + lane] = make_float2(a0, a1);
  }
  float hl0[2], hl1[2];
#pragma unroll
  for (int rr = 0; rr < 2; rr++) {
    float2 hh = Pr[(size_t)(r0 + rr) * 64 + lane];
    hl0[rr] = hh.x;  // h0(k-1): cell0 liWh0 + cell1 liWi1
    hl1[rr] = hh.y;  // h1(k-2): cell1 liWh1
  }

  // accumulator inits: bias/x terms live in exactly one k-half
  float4 acc0[2], acc1[2];
  if (kh == 0) {
    float4 b = biasg0[lane];
    float4 qg0 = xq0[lane], qg1 = xq0[64 + lane];
    float4 ql0 = xq0[128 + lane], ql1 = xq0[192 + lane];
#pragma unroll
    for (int rr = 0; rr < 2; rr++) {
      float xx0 = xt[(size_t)(r0 + rr) * 2];
      float xx1 = xt[(size_t)(r0 + rr) * 2 + 1];
      float gg0 = gaxt[(size_t)(r0 + rr) * 2];
      float gg1 = gaxt[(size_t)(r0 + rr) * 2 + 1];
      acc0[rr].x = b.x + gg0 * qg0.x + gg1 * qg1.x + xx0 * ql0.x + xx1 * ql1.x;
      acc0[rr].y = b.y + gg0 * qg0.y + gg1 * qg1.y + xx0 * ql0.y + xx1 * ql1.y;
      acc0[rr].z = b.z + gg0 * qg0.z + gg1 * qg1.z + xx0 * ql0.z + xx1 * ql1.z;
      acc0[rr].w = b.w + gg0 * qg0.w + gg1 * qg1.w + xx0 * ql0.w + xx1 * ql1.w;
    }
    acc1[0] = make_float4(0.f, 0.f, 0.f, 0.f);
    acc1[1] = make_float4(0.f, 0.f, 0.f, 0.f);
  } else {
    acc0[0] = make_float4(0.f, 0.f, 0.f, 0.f);
    acc0[1] = make_float4(0.f, 0.f, 0.f, 0.f);
    float4 b1 = biasg1[lane];
    acc1[0] = b1; acc1[1] = b1;
  }

  // stage chunk 0; barrier makes gx + chunk0 visible
  wbuf[tid] = st0; wbuf[512 + tid] = st1;
  __syncthreads();

  // read pair's ga for both rows
  float ga0[2], ga1[2];
  {
    const float2* gx = (const float2*)xbuf;
#pragma unroll
    for (int rr = 0; rr < 2; rr++) {
      float2 g = gx[(size_t)(pair * 2 + rr) * 64 + lane];
      ga0[rr] = g.x;  // A@h0(k-1): cell0 gcWh0 + cell1 gcWi1
      ga1[rr] = g.y;  // A@h1(k-2): cell1 gcWh1
    }
  }

  int cur = 0;
  // loop A: Wg0, 8 chunks; each wave computes its 4 k's per chunk.
  // ALWAYS prefetch next (ch=7 pulls Wg1 chunk 0 across the boundary).
#pragma unroll 1
  for (int ch = 0; ch < 8; ch++) {
    st0 = pf[0]; st1 = pf[512];
    pf += 1024;
    const float4* wb = wbuf + (cur << 10);
    const int kb = kh * 32 + ch * 4;
    const int wbase = kh * 4;
#pragma unroll
    for (int q = 0; q < 4; q++) {
      int k = kb + q;
      float4 w0 = wb[(wbase + q) * 128 + lane];
      float4 w1 = wb[(wbase + q) * 128 + 64 + lane];
#pragma unroll
      for (int rr = 0; rr < 2; rr++) {
        float b0 = bcast_f(ga0[rr], k);
        float b1 = bcast_f(hl0[rr], k);
        acc0[rr].x += b0 * w0.x + b1 * w1.x;
        acc0[rr].y += b0 * w0.y + b1 * w1.y;
        acc0[rr].z += b0 * w0.z + b1 * w1.z;
        acc0[rr].w += b0 * w0.w + b1 * w1.w;
      }
    }
    cur ^= 1;
    float4* dst = wbuf + (cur << 10) + tid;
    dst[0] = st0; dst[512] = st1;
    if (ch == 7 && kh == 1) {  // stash acc0 partials before the barrier
      xbuf[(size_t)(pair * 2 + 0) * 64 + lane] = acc0[0];
      xbuf[(size_t)(pair * 2 + 1) * 64 + lane] = acc0[1];
    }
    __syncthreads();  // writes + stash visible; all waves past chunk ch
  }

  // cell0 reduce + epilogue (kh=0); overlaps kh=1's loop-B start
  if (c0on && kh == 0) {
#pragma unroll
    for (int rr = 0; rr < 2; rr++) {
      float4 o = xbuf[(size_t)(pair * 2 + rr) * 64 + lane];
      float gxv = acc0[rr].x + o.x, gyv = acc0[rr].y + o.y;
      float gzv = acc0[rr].z + o.z, gwv = acc0[rr].w + o.w;
      size_t gi = (size_t)(r0 + rr) * HH + lane;
      float si = 1.0f / (1.0f + __expf(-gxv));
      float sf = 1.0f / (1.0f + __expf(-gyv));
      float so = 1.0f / (1.0f + __expf(-gzv));
      float cn = sf * cprevA[rr] + si * tanhf(gwv);
      float hn = so * tanhf(cn);
      c0[gi] = cn;
      Pw[gi * 2 + 0] = hn;
    }
  }

  // loop B: Wg1, 16 chunks; each wave computes its 2 k's per chunk.
  // buf[cur] already holds Wg1 chunk 0 (staged at ch=7 above).
#pragma unroll 1
  for (int ch = 0; ch < 16; ch++) {
    if (ch + 1 < 16) {
      st0 = pf[0]; st1 = pf[512];
      pf += 1024;
    }
    const float4* wb = wbuf + (cur << 10);
    const int kb = kh * 32 + ch * 2;
    const int wbase = kh * 2;
#pragma unroll
    for (int q = 0; q < 2; q++) {
      int k = kb + q;
      const float4* wp = wb + (wbase + q) * 256 + lane;
      float4 w0 = wp[0], w1 = wp[64], w2 = wp[128], w3 = wp[192];
#pragma unroll
      for (int rr = 0; rr < 2; rr++) {
        float b0 = bcast_f(ga0[rr], k);   // (A@h0new)  -> gcWi1
        float b1 = bcast_f(hl0[rr], k);   // h0new      -> liWi1
        float b2 = bcast_f(ga1[rr], k);   // (A@h1old)  -> gcWh1
        float b3 = bcast_f(hl1[rr], k);   // h1old      -> liWh1
        acc1[rr].x += b0 * w0.x + b1 * w1.x + b2 * w2.x + b3 * w3.x;
        acc1[rr].y += b0 * w0.y + b1 * w1.y + b2 * w2.y + b3 * w3.y;
        acc1[rr].z += b0 * w0.z + b1 * w1.z + b2 * w2.z + b3 * w3.z;
        acc1[rr].w += b0 * w0.w + b1 * w1.w + b2 * w2.w + b3 * w3.w;
      }
    }
    if (ch + 1 < 16) {
      cur ^= 1;
      float4* dst = wbuf + (cur << 10) + tid;
      dst[0] = st0; dst[512] = st1;
      __syncthreads();
    }
  }

  // cell1 reduce + epilogue (kh=1)
  if (c1on) {
    if (kh == 0) {  // stash acc1 partials (xbuf free: last read after loop A)
      xbuf[(size_t)(pair * 2 + 0) * 64 + lane] = acc1[0];
      xbuf[(size_t)(pair * 2 + 1) * 64 + lane] = acc1[1];
    }
    __syncthreads();
    if (kh == 1) {
#pragma unroll
      for (int rr = 0; rr < 2; rr++) {
        float4 o = xbuf[(size_t)(pair * 2 + rr) * 64 + lane];
        float gxv = acc1[rr].x + o.x, gyv = acc1[rr].y + o.y;
        float gzv = acc1[rr].z + o.z, gwv = acc1[rr].w + o.w;
        size_t gi = (size_t)(r0 + rr) * HH + lane;
        float si = 1.0f / (1.0f + __expf(-gxv));
        float sf = 1.0f / (1.0f + __expf(-gyv));
        float so = 1.0f / (1.0f + __expf(-gzv));
        float cn = sf * cprevA[rr] + si * tanhf(gwv);
        float hn = so * tanhf(cn);
        c1[gi] = cn;
        Pw[gi * 2 + 1] = hn;
      }
    }
  }
}

// ---------------------------------------------------------------------------
// Output projection: out[r,p] = h1[r,:] @ outW[:,p] + outb[p].
// h1 final = P0[..][1] (launch 48 writes P[0].y).
// ---------------------------------------------------------------------------
__launch_bounds__(256)
__global__ void k_out(const float* __restrict__ P0, const float* __restrict__ outW,
                      const float* __restrict__ outb, float* __restrict__ out) {
  int idx = blockIdx.x * 256 + threadIdx.x;
  if (idx >= NN * PP) return;
  int r = idx / PP, p = idx - r * PP;
  float acc = outb[p];
  const float* hrow = P0 + (size_t)r * 128;
#pragma unroll 16
  for (int k = 0; k < HH; k++) acc += hrow[k * 2 + 1] * outW[k * PP + p];
  out[idx] = acc;
}

extern "C" void kernel_launch(void* const* d_in, const int* in_sizes, int n_in,
                              void* d_out, int out_size, void* d_ws, size_t ws_size,
                              hipStream_t stream) {
  const float* x     = (const float*)d_in[0];
  const float* adj   = (const float*)d_in[1];
  const float* gcWi0 = (const float*)d_in[2];
  const float* gcbi0 = (const float*)d_in[3];
  const float* gcWh0 = (const float*)d_in[4];
  const float* gcbh0 = (const float*)d_in[5];
  const float* liWi0 = (const float*)d_in[6];
  const float* libi0 = (const float*)d_in[7];
  const float* liWh0 = (const float*)d_in[8];
  const float* libh0 = (const float*)d_in[9];
  const float* gcWi1 = (const float*)d_in[10];
  const float* gcbi1 = (const float*)d_in[11];
  const float* gcWh1 = (const float*)d_in[12];
  const float* gcbh1 = (const float*)d_in[13];
  const float* liWi1 = (const float*)d_in[14];
  const float* libi1 = (const float*)d_in[15];
  const float* liWh1 = (const float*)d_in[16];
  const float* libh1 = (const float*)d_in[17];
  const float* outW  = (const float*)d_in[18];
  const float* outb  = (const float*)d_in[19];

  char* ws = (char*)d_ws;
  size_t off = 0;
  auto carve = [&](size_t bytes) {
    void* p = ws + off;
    off += (bytes + 255) & ~(size_t)255;
    return p;
  };
  float*  dinv    = (float*)carve((size_t)NN * 4);
  int*    ell_col = (int*)carve((size_t)NN * CAP * 4);
  float*  ell_val = (float*)carve((size_t)NN * CAP * 4);
  int*    ell_cnt = (int*)carve((size_t)NN * 4);
  float*  state   = (float*)carve((size_t)6 * NH * 4);  // P0,P1 (2NH each), c0, c1
  float*  gax     = (float*)carve((size_t)TT * NN * 2 * 4);
  float4* Wgm     = (float4*)carve((size_t)(8192 + 16384) * 16);  // Wg0|Wg1 contiguous
  float4* biasg0  = (float4*)carve((size_t)64 * 16);
  float4* biasg1  = (float4*)carve((size_t)64 * 16);
  float4* xq0     = (float4*)carve((size_t)256 * 16);

  float4* Wg0 = Wgm;
  float4* Wg1 = Wgm + 8192;
  float* P[2] = {state, state + 2 * NH};
  float* c0 = state + 4 * NH;
  float* c1 = state + 5 * NH;

  k_prep<<<512, 256, 0, stream>>>(gcbi0, gcbh0, libi0, libh0,
                                  gcbi1, gcbh1, libi1, libh1,
                                  gcWh0, liWh0, gcWi1, liWi1, gcWh1, liWh1,
                                  gcWi0, liWi0,
                                  state, Wg0, Wg1, biasg0, biasg1, xq0);
  k_build<<<NN, 256, 0, stream>>>(adj, dinv, ell_col, ell_val, ell_cnt);
  k_scale<<<(NN * CAP) / 256, 256, 0, stream>>>(dinv, ell_col, ell_val);
  k_gax<<<TT * 8, 256, 0, stream>>>(x, ell_col, ell_val, ell_cnt, gax);

  // Merged k-split step loop: launch k runs {cell0(k) + cell1(k-1)} per
  // 8-row 512-thread block. Launch k reads P[(k&1)^1], writes P[k&1].
  for (int k = 0; k <= TT; k++) {
    int A = k & 1;
    int c0on = (k < TT) ? 1 : 0;
    int c1on = (k > 0) ? 1 : 0;
    int tx = (k < TT) ? k : (TT - 1);              // xt/gaxt unused when k==TT
    k_cells<<<NN / 8, 512, 0, stream>>>(
        c0on, c1on, ell_col, ell_val, ell_cnt,
        (const float2*)P[A ^ 1], P[A], c0, c1,
        x + (size_t)tx * NN * 2, gax + (size_t)tx * NN * 2,
        Wgm, biasg0, xq0, biasg1);
  }

  // Launch 48 (A=0) wrote h1(47) into P[0].y
  k_out<<<(NN * PP + 255) / 256, 256, 0, stream>>>(P[0], outW, outb, (float*)d_out);
}